// Round 1
// 832.356 us; speedup vs baseline: 1.2997x; 1.2997x over previous
//
#include <hip/hip_runtime.h>

typedef __attribute__((ext_vector_type(8))) short short8;
typedef __attribute__((ext_vector_type(4))) float float4v;
typedef unsigned int u32;

#define K_DIM 4096
#define O_DIM 11008
#define KP    2048   // packed int32 per output row (1 byte of codes per int32)
#define NBLK  64     // absmax blocks per row
#define BM    128
#define BN    128
#define BK    64
#define LDT   72     // padded LDS row stride for the fused fallback kernel

// NF4 table via immediate-literal select tree (no device globals).
__device__ __forceinline__ float nf4_val(int c) {
    float v = -1.0f;
    v = (c == 1)  ? -0.6961928009986877f   : v;
    v = (c == 2)  ? -0.5250730514526367f   : v;
    v = (c == 3)  ? -0.39491748809814453f  : v;
    v = (c == 4)  ? -0.28444138169288635f  : v;
    v = (c == 5)  ? -0.18477343022823334f  : v;
    v = (c == 6)  ? -0.09105003625154495f  : v;
    v = (c == 7)  ? 0.0f                   : v;
    v = (c == 8)  ? 0.07958029955625534f   : v;
    v = (c == 9)  ? 0.16093020141124725f   : v;
    v = (c == 10) ? 0.24611230194568634f   : v;
    v = (c == 11) ? 0.33791524171829224f   : v;
    v = (c == 12) ? 0.44070982933044434f   : v;
    v = (c == 13) ? 0.5626170039176941f    : v;
    v = (c == 14) ? 0.8072066307067871f    : v;
    v = (c == 15) ? 1.0f                   : v;
    return v;
}

__device__ __forceinline__ unsigned short bf16_rne(float f) {
    unsigned int u = __float_as_uint(f);
    u = (u + 0x7FFFu + ((u >> 16) & 1u)) >> 16;
    return (unsigned short)u;
}

__device__ __forceinline__ unsigned int pack_bf16x2(float lo_k, float hi_k) {
    // halfword0 (low) = smaller k index (little-endian layout)
    return (unsigned int)bf16_rne(lo_k) | ((unsigned int)bf16_rne(hi_k) << 16);
}

// async global->LDS, 16 B per lane; LDS dest is wave-uniform base + lane*16.
__device__ __forceinline__ void gload_lds16(const unsigned short* g, unsigned short* l) {
    __builtin_amdgcn_global_load_lds((const __attribute__((address_space(1))) u32*)g,
                                     (__attribute__((address_space(3))) u32*)l,
                                     16, 0, 0);
}

// ---------------------------------------------------------------------------
// Prep pass 1: X f32 -> bf16 (memory-bound)
// ---------------------------------------------------------------------------
__global__ __launch_bounds__(256) void cvt_x_kernel(
    const float* __restrict__ X, unsigned short* __restrict__ Xb, int nchunk)
{
    int i = blockIdx.x * 256 + threadIdx.x;
    if (i >= nchunk) return;
    const float* p = X + (size_t)i * 8;
    float4v a = *(const float4v*)p;
    float4v b = *(const float4v*)(p + 4);
    uint4 o;
    o.x = pack_bf16x2(a.x, a.y);
    o.y = pack_bf16x2(a.z, a.w);
    o.z = pack_bf16x2(b.x, b.y);
    o.w = pack_bf16x2(b.z, b.w);
    *(uint4*)(Xb + (size_t)i * 8) = o;
}

// ---------------------------------------------------------------------------
// Prep pass 2: NF4 W -> bf16 (dequantized ONCE instead of once per m-block)
// ---------------------------------------------------------------------------
__global__ __launch_bounds__(256) void dequant_w_kernel(
    const int* __restrict__ Wp, const float* __restrict__ Smax,
    unsigned short* __restrict__ Wb)
{
    __shared__ unsigned int T2[256];   // byte -> packed bf16 pair (unscaled)
    {
        const int t = threadIdx.x;
        unsigned int hi = (unsigned int)bf16_rne(nf4_val(t >> 4));
        unsigned int lo = (unsigned int)bf16_rne(nf4_val(t & 15));
        T2[t] = hi | (lo << 16);
    }
    __syncthreads();

    const int idx = blockIdx.x * 256 + threadIdx.x;  // chunk id: 11008*512 total, exact grid
    const int row = idx >> 9;        // output row
    const int c   = idx & 511;       // 16B chunk within row (8 bf16 out)

    uint4 wv = *(const uint4*)(Wp + (size_t)row * KP + c * 4);
    const float s0 = Smax[row * NBLK + (c >> 3)];   // BK-block = 8 chunks
    unsigned int vv[4] = {wv.x, wv.y, wv.z, wv.w};
    unsigned int od[4];
#pragma unroll
    for (int j = 0; j < 4; ++j) {
        const unsigned int pair = T2[vv[j] & 0xFFu];
        const float fe = __uint_as_float(pair << 16) * s0;           // k even (hi nibble)
        const float fo = __uint_as_float(pair & 0xFFFF0000u) * s0;   // k odd  (lo nibble)
        od[j] = pack_bf16x2(fe, fo);
    }
    uint4 ov; ov.x = od[0]; ov.y = od[1]; ov.z = od[2]; ov.w = od[3];
    *(uint4*)(Wb + (size_t)row * K_DIM + c * 8) = ov;
}

// ---------------------------------------------------------------------------
// Main GEMM: bf16, m97 structure (128x128 tile, BK=64, linear LDS,
// global_load_lds width-16, 2 barriers per K-step)
// ---------------------------------------------------------------------------
__global__ __launch_bounds__(256) void gemm_bf16_kernel(
    const unsigned short* __restrict__ Xb,   // [M][4096] bf16
    const unsigned short* __restrict__ Wb,   // [11008][4096] bf16
    const float* __restrict__ Bias,
    float* __restrict__ Out, int M)
{
    __shared__ unsigned short Atile[BM * BK];   // 16 KB, linear
    __shared__ unsigned short Btile[BN * BK];   // 16 KB, linear

    const int t    = threadIdx.x;
    const int lane = t & 63;
    const int wave = t >> 6;
    const int m0 = blockIdx.x * BM;   // m fastest: consecutive blocks share B slab
    const int n0 = blockIdx.y * BN;
    const int wm = (wave >> 1) * 64;
    const int wn = (wave & 1) * 64;

    const int srow = lane >> 3;         // 0..7: row within 8-row stripe
    const int schk = (lane & 7) * 8;    // element offset within row

    float4v acc[4][4] = {};

    for (int s = 0; s < K_DIM / BK; ++s) {
        const int kt = s * BK;
        // each wave stages rows [32*wave, 32*wave+32) of both tiles:
        // 4 stripes of 8 rows, 1 KB per global_load_lds (64 lanes x 16 B)
#pragma unroll
        for (int q = 0; q < 4; ++q) {
            const int r = 32 * wave + 8 * q + srow;
            gload_lds16(Xb + (size_t)(m0 + r) * K_DIM + kt + schk,
                        &Atile[(32 * wave + 8 * q) * BK]);
            gload_lds16(Wb + (size_t)(n0 + r) * K_DIM + kt + schk,
                        &Btile[(32 * wave + 8 * q) * BK]);
        }
        __syncthreads();   // compiler drains vmcnt(0) before s_barrier

#pragma unroll
        for (int k2 = 0; k2 < 2; ++k2) {
            const int ks = k2 * 32 + (lane >> 4) * 8;
            short8 af[4], bfv[4];
#pragma unroll
            for (int i = 0; i < 4; ++i)
                af[i] = *(const short8*)&Atile[(wm + i * 16 + (lane & 15)) * BK + ks];
#pragma unroll
            for (int j = 0; j < 4; ++j)
                bfv[j] = *(const short8*)&Btile[(wn + j * 16 + (lane & 15)) * BK + ks];
#pragma unroll
            for (int i = 0; i < 4; ++i)
#pragma unroll
                for (int j = 0; j < 4; ++j)
                    acc[i][j] = __builtin_amdgcn_mfma_f32_16x16x32_bf16(
                        af[i], bfv[j], acc[i][j], 0, 0, 0);
        }
        __syncthreads();
    }

    // epilogue: D layout col = lane&15, row = (lane>>4)*4 + reg
#pragma unroll
    for (int j = 0; j < 4; ++j) {
        const int col = n0 + wn + j * 16 + (lane & 15);
        const float bj = Bias[col];
#pragma unroll
        for (int i = 0; i < 4; ++i) {
            const int rowb = m0 + wm + i * 16 + ((lane >> 4) << 2);
#pragma unroll
            for (int r = 0; r < 4; ++r) {
                Out[(size_t)(rowb + r) * O_DIM + col] = acc[i][j][r] + bj;
            }
        }
    }
}

// ---------------------------------------------------------------------------
// Fused fallback (previous kernel, unchanged) — used if workspace too small
// ---------------------------------------------------------------------------
__global__ __launch_bounds__(256) void nf4_linear_kernel(
    const float* __restrict__ X,
    const int* __restrict__ Wp,
    const float* __restrict__ Smax,
    const float* __restrict__ Bias,
    float* __restrict__ Out,
    int M)
{
    __shared__ unsigned short Atile[BM * LDT];
    __shared__ unsigned short Btile[BN * LDT];
    __shared__ unsigned int   T2[256];

    const int t = threadIdx.x;
    const int m0 = blockIdx.x * BM;
    const int n0 = blockIdx.y * BN;

    {
        unsigned int hi = (unsigned int)bf16_rne(nf4_val(t >> 4));
        unsigned int lo = (unsigned int)bf16_rne(nf4_val(t & 15));
        T2[t] = hi | (lo << 16);
    }
    __syncthreads();

    const int lane = t & 63;
    const int wave = t >> 6;
    const int wm = (wave >> 1) * 64;
    const int wn = (wave & 1) * 64;
    const int ar = t >> 3;
    const int ach = t & 7;

    float4v acc[4][4] = {};

    for (int s = 0; s < K_DIM / BK; ++s) {
        const int kt = s * BK;
        float4v a0[4], a1[4]; uint4 wL[4]; float sc[4];
#pragma unroll
        for (int i = 0; i < 4; ++i) {
            const int row = ar + 32 * i;
            const float* ap = X + (size_t)(m0 + row) * K_DIM + kt + ach * 8;
            a0[i] = *(const float4v*)ap;
            a1[i] = *(const float4v*)(ap + 4);
            wL[i] = *(const uint4*)(Wp + (size_t)(n0 + row) * KP + (kt >> 1) + ach * 4);
            sc[i] = Smax[(n0 + row) * NBLK + s];
        }
#pragma unroll
        for (int i = 0; i < 4; ++i) {
            const int row = ar + 32 * i;
            uint4 av;
            av.x = pack_bf16x2(a0[i].x, a0[i].y);
            av.y = pack_bf16x2(a0[i].z, a0[i].w);
            av.z = pack_bf16x2(a1[i].x, a1[i].y);
            av.w = pack_bf16x2(a1[i].z, a1[i].w);
            *(uint4*)&Atile[row * LDT + ach * 8] = av;

            const float s0 = sc[i];
            unsigned int wv[4] = {(unsigned int)wL[i].x, (unsigned int)wL[i].y,
                                  (unsigned int)wL[i].z, (unsigned int)wL[i].w};
            unsigned int od[4];
#pragma unroll
            for (int j = 0; j < 4; ++j) {
                const unsigned int pair = T2[wv[j] & 0xFFu];
                const float fe = __uint_as_float(pair << 16) * s0;
                const float fo = __uint_as_float(pair & 0xFFFF0000u) * s0;
                od[j] = pack_bf16x2(fe, fo);
            }
            uint4 ov; ov.x = od[0]; ov.y = od[1]; ov.z = od[2]; ov.w = od[3];
            *(uint4*)&Btile[row * LDT + ach * 8] = ov;
        }
        __syncthreads();

#pragma unroll
        for (int k2 = 0; k2 < 2; ++k2) {
            const int ks = k2 * 32 + (lane >> 4) * 8;
            short8 af[4], bfv[4];
#pragma unroll
            for (int i = 0; i < 4; ++i)
                af[i] = *(const short8*)&Atile[(wm + i * 16 + (lane & 15)) * LDT + ks];
#pragma unroll
            for (int j = 0; j < 4; ++j)
                bfv[j] = *(const short8*)&Btile[(wn + j * 16 + (lane & 15)) * LDT + ks];
#pragma unroll
            for (int i = 0; i < 4; ++i)
#pragma unroll
                for (int j = 0; j < 4; ++j)
                    acc[i][j] = __builtin_amdgcn_mfma_f32_16x16x32_bf16(
                        af[i], bfv[j], acc[i][j], 0, 0, 0);
        }
        __syncthreads();
    }

#pragma unroll
    for (int j = 0; j < 4; ++j) {
        const int col = n0 + wn + j * 16 + (lane & 15);
        const float bj = Bias[col];
#pragma unroll
        for (int i = 0; i < 4; ++i) {
            const int rowb = m0 + wm + i * 16 + ((lane >> 4) << 2);
#pragma unroll
            for (int r = 0; r < 4; ++r) {
                Out[(size_t)(rowb + r) * O_DIM + col] = acc[i][j][r] + bj;
            }
        }
    }
}

extern "C" void kernel_launch(void* const* d_in, const int* in_sizes, int n_in,
                              void* d_out, int out_size, void* d_ws, size_t ws_size,
                              hipStream_t stream) {
    const float* X    = (const float*)d_in[0];
    const int*   Wp   = (const int*)d_in[1];
    const float* Smax = (const float*)d_in[2];
    const float* Bias = (const float*)d_in[3];
    float*       Out  = (float*)d_out;

    const int M = in_sizes[0] / K_DIM;   // 4096

    const size_t xb_bytes = (size_t)M * K_DIM * sizeof(unsigned short);      // 33.5 MB
    const size_t wb_bytes = (size_t)O_DIM * K_DIM * sizeof(unsigned short);  // 90.2 MB

    if (ws_size >= xb_bytes + wb_bytes) {
        unsigned short* Xb = (unsigned short*)d_ws;
        unsigned short* Wb = (unsigned short*)((char*)d_ws + xb_bytes);

        const int nchunk_x = (M * K_DIM) / 8;                      // 2,097,152
        cvt_x_kernel<<<dim3((nchunk_x + 255) / 256), dim3(256), 0, stream>>>(X, Xb, nchunk_x);

        const int nchunk_w = O_DIM * (KP / 4);                     // 5,636,096 (exact /256)
        dequant_w_kernel<<<dim3(nchunk_w / 256), dim3(256), 0, stream>>>(Wp, Smax, Wb);

        dim3 grid(M / BM, O_DIM / BN);   // (32, 86), m fastest for B-slab L2 reuse
        gemm_bf16_kernel<<<grid, dim3(256), 0, stream>>>(Xb, Wb, Bias, Out, M);
    } else {
        dim3 grid(M / BM, O_DIM / BN);
        nf4_linear_kernel<<<grid, dim3(256), 0, stream>>>(X, Wp, Smax, Bias, Out, M);
    }
}

// Round 2
// 816.671 us; speedup vs baseline: 1.3247x; 1.0192x over previous
//
#include <hip/hip_runtime.h>

typedef __attribute__((ext_vector_type(8))) short short8;
typedef __attribute__((ext_vector_type(4))) float float4v;
typedef unsigned int u32;

#define K_DIM 4096
#define O_DIM 11008
#define KP    2048   // packed int32 per output row (1 byte of codes per int32)
#define NBLK  64     // absmax blocks per row
#define BM    128
#define BN    128
#define BK    64
#define LDT   72     // padded LDS row stride for the fused fallback kernel

// NF4 table via immediate-literal select tree (no device globals).
__device__ __forceinline__ float nf4_val(int c) {
    float v = -1.0f;
    v = (c == 1)  ? -0.6961928009986877f   : v;
    v = (c == 2)  ? -0.5250730514526367f   : v;
    v = (c == 3)  ? -0.39491748809814453f  : v;
    v = (c == 4)  ? -0.28444138169288635f  : v;
    v = (c == 5)  ? -0.18477343022823334f  : v;
    v = (c == 6)  ? -0.09105003625154495f  : v;
    v = (c == 7)  ? 0.0f                   : v;
    v = (c == 8)  ? 0.07958029955625534f   : v;
    v = (c == 9)  ? 0.16093020141124725f   : v;
    v = (c == 10) ? 0.24611230194568634f   : v;
    v = (c == 11) ? 0.33791524171829224f   : v;
    v = (c == 12) ? 0.44070982933044434f   : v;
    v = (c == 13) ? 0.5626170039176941f    : v;
    v = (c == 14) ? 0.8072066307067871f    : v;
    v = (c == 15) ? 1.0f                   : v;
    return v;
}

__device__ __forceinline__ unsigned short bf16_rne(float f) {
    unsigned int u = __float_as_uint(f);
    u = (u + 0x7FFFu + ((u >> 16) & 1u)) >> 16;
    return (unsigned short)u;
}

__device__ __forceinline__ unsigned int pack_bf16x2(float lo_k, float hi_k) {
    return (unsigned int)bf16_rne(lo_k) | ((unsigned int)bf16_rne(hi_k) << 16);
}

// async global->LDS, 16 B per lane; LDS dest is wave-uniform base + lane*16.
__device__ __forceinline__ void gload_lds16(const unsigned short* g, unsigned short* l) {
    __builtin_amdgcn_global_load_lds((const __attribute__((address_space(1))) u32*)g,
                                     (__attribute__((address_space(3))) u32*)l,
                                     16, 0, 0);
}

// ---------------------------------------------------------------------------
// Prep pass 1: X f32 -> bf16 (memory-bound), grid-stride
// ---------------------------------------------------------------------------
__global__ __launch_bounds__(256) void cvt_x_kernel(
    const float* __restrict__ X, unsigned short* __restrict__ Xb, int nchunk)
{
    const int stride = gridDim.x * 256;
    for (int i = blockIdx.x * 256 + threadIdx.x; i < nchunk; i += stride) {
        const float* p = X + (size_t)i * 8;
        float4v a = *(const float4v*)p;
        float4v b = *(const float4v*)(p + 4);
        uint4 o;
        o.x = pack_bf16x2(a.x, a.y);
        o.y = pack_bf16x2(a.z, a.w);
        o.z = pack_bf16x2(b.x, b.y);
        o.w = pack_bf16x2(b.z, b.w);
        *(uint4*)(Xb + (size_t)i * 8) = o;
    }
}

// ---------------------------------------------------------------------------
// Prep pass 2: NF4 W -> bf16 (dequantized ONCE), grid-stride
// ---------------------------------------------------------------------------
__global__ __launch_bounds__(256) void dequant_w_kernel(
    const int* __restrict__ Wp, const float* __restrict__ Smax,
    unsigned short* __restrict__ Wb, int nchunk)
{
    __shared__ unsigned int T2[256];   // byte -> packed bf16 pair (unscaled)
    {
        const int t = threadIdx.x;
        unsigned int hi = (unsigned int)bf16_rne(nf4_val(t >> 4));
        unsigned int lo = (unsigned int)bf16_rne(nf4_val(t & 15));
        T2[t] = hi | (lo << 16);
    }
    __syncthreads();

    const int stride = gridDim.x * 256;
    for (int idx = blockIdx.x * 256 + threadIdx.x; idx < nchunk; idx += stride) {
        const int row = idx >> 9;        // output row
        const int c   = idx & 511;       // 16B chunk within row (8 bf16 out)

        uint4 wv = *(const uint4*)(Wp + (size_t)row * KP + c * 4);
        const float s0 = Smax[row * NBLK + (c >> 3)];
        unsigned int vv[4] = {wv.x, wv.y, wv.z, wv.w};
        unsigned int od[4];
#pragma unroll
        for (int j = 0; j < 4; ++j) {
            const unsigned int pair = T2[vv[j] & 0xFFu];
            const float fe = __uint_as_float(pair << 16) * s0;           // k even (hi nibble)
            const float fo = __uint_as_float(pair & 0xFFFF0000u) * s0;   // k odd  (lo nibble)
            od[j] = pack_bf16x2(fe, fo);
        }
        uint4 ov; ov.x = od[0]; ov.y = od[1]; ov.z = od[2]; ov.w = od[3];
        *(uint4*)(Wb + (size_t)row * K_DIM + c * 8) = ov;
    }
}

// ---------------------------------------------------------------------------
// Main GEMM: bf16, m97 structure + XOR-swizzled LDS (linear dest, pre-swizzled
// global source, swizzled ds_read) + XCD-bijective grid swizzle + setprio.
// ---------------------------------------------------------------------------
__global__ __launch_bounds__(256) void gemm_bf16_kernel(
    const unsigned short* __restrict__ Xb,   // [M][4096] bf16
    const unsigned short* __restrict__ Wb,   // [11008][4096] bf16
    const float* __restrict__ Bias,
    float* __restrict__ Out, int M)
{
    __shared__ unsigned short Atile[BM * BK];   // 16 KB, linear (swizzled content)
    __shared__ unsigned short Btile[BN * BK];   // 16 KB, linear (swizzled content)

    const int t    = threadIdx.x;
    const int lane = t & 63;
    const int wave = t >> 6;

    // XCD-bijective swizzle of the flattened 1D grid (T1, m204 variant)
    const int nm   = M / BM;                 // m-tiles (32)
    const int nwg  = gridDim.x;              // 2752
    const int q    = nwg >> 3, r = nwg & 7;
    const int xcd  = blockIdx.x & 7;
    const int wg   = (xcd < r ? xcd * (q + 1) : r * (q + 1) + (xcd - r) * q)
                   + (blockIdx.x >> 3);
    const int m0 = (wg % nm) * BM;           // m fastest within an XCD chunk
    const int n0 = (wg / nm) * BN;

    const int wm = (wave >> 1) * 64;
    const int wn = (wave & 1) * 64;

    // staging geometry: stripes of 8 rows x 8 slots of 16B.
    // LDS stays LINEAR; the SOURCE slot is XOR-swizzled so that
    // LDS(row, s) = G(row, s ^ (row&7)).
    const int srow  = lane >> 3;                 // row within stripe (0..7)
    const int sslot = (lane & 7) ^ srow;         // pre-swizzled source slot

    float4v acc[4][4] = {};

    for (int s = 0; s < K_DIM / BK; ++s) {
        const int kt = s * BK;
#pragma unroll
        for (int qq = 0; qq < 4; ++qq) {
            const int r8 = 32 * wave + 8 * qq;   // stripe base row (mult of 8)
            gload_lds16(Xb + (size_t)(m0 + r8 + srow) * K_DIM + kt + sslot * 8,
                        &Atile[r8 * BK]);
            gload_lds16(Wb + (size_t)(n0 + r8 + srow) * K_DIM + kt + sslot * 8,
                        &Btile[r8 * BK]);
        }
        __syncthreads();   // drains vmcnt(0) before s_barrier

#pragma unroll
        for (int k2 = 0; k2 < 2; ++k2) {
            // logical 16B slot this lane needs: k2*4 + quarter-group
            const int sx = ((k2 * 4 + (lane >> 4)) ^ (lane & 7)) * 8;
            short8 af[4], bfv[4];
#pragma unroll
            for (int i = 0; i < 4; ++i)
                af[i] = *(const short8*)&Atile[(wm + i * 16 + (lane & 15)) * BK + sx];
#pragma unroll
            for (int j = 0; j < 4; ++j)
                bfv[j] = *(const short8*)&Btile[(wn + j * 16 + (lane & 15)) * BK + sx];

            __builtin_amdgcn_s_setprio(1);
#pragma unroll
            for (int i = 0; i < 4; ++i)
#pragma unroll
                for (int j = 0; j < 4; ++j)
                    acc[i][j] = __builtin_amdgcn_mfma_f32_16x16x32_bf16(
                        af[i], bfv[j], acc[i][j], 0, 0, 0);
            __builtin_amdgcn_s_setprio(0);
        }
        __syncthreads();
    }

    // epilogue: D layout col = lane&15, row = (lane>>4)*4 + reg
#pragma unroll
    for (int j = 0; j < 4; ++j) {
        const int col = n0 + wn + j * 16 + (lane & 15);
        const float bj = Bias[col];
#pragma unroll
        for (int i = 0; i < 4; ++i) {
            const int rowb = m0 + wm + i * 16 + ((lane >> 4) << 2);
#pragma unroll
            for (int rr = 0; rr < 4; ++rr) {
                Out[(size_t)(rowb + rr) * O_DIM + col] = acc[i][j][rr] + bj;
            }
        }
    }
}

// ---------------------------------------------------------------------------
// Fused fallback (verified) — used if workspace too small
// ---------------------------------------------------------------------------
__global__ __launch_bounds__(256) void nf4_linear_kernel(
    const float* __restrict__ X,
    const int* __restrict__ Wp,
    const float* __restrict__ Smax,
    const float* __restrict__ Bias,
    float* __restrict__ Out,
    int M)
{
    __shared__ unsigned short Atile[BM * LDT];
    __shared__ unsigned short Btile[BN * LDT];
    __shared__ unsigned int   T2[256];

    const int t = threadIdx.x;
    const int m0 = blockIdx.x * BM;
    const int n0 = blockIdx.y * BN;

    {
        unsigned int hi = (unsigned int)bf16_rne(nf4_val(t >> 4));
        unsigned int lo = (unsigned int)bf16_rne(nf4_val(t & 15));
        T2[t] = hi | (lo << 16);
    }
    __syncthreads();

    const int lane = t & 63;
    const int wave = t >> 6;
    const int wm = (wave >> 1) * 64;
    const int wn = (wave & 1) * 64;
    const int ar = t >> 3;
    const int ach = t & 7;

    float4v acc[4][4] = {};

    for (int s = 0; s < K_DIM / BK; ++s) {
        const int kt = s * BK;
        float4v a0[4], a1[4]; uint4 wL[4]; float sc[4];
#pragma unroll
        for (int i = 0; i < 4; ++i) {
            const int row = ar + 32 * i;
            const float* ap = X + (size_t)(m0 + row) * K_DIM + kt + ach * 8;
            a0[i] = *(const float4v*)ap;
            a1[i] = *(const float4v*)(ap + 4);
            wL[i] = *(const uint4*)(Wp + (size_t)(n0 + row) * KP + (kt >> 1) + ach * 4);
            sc[i] = Smax[(n0 + row) * NBLK + s];
        }
#pragma unroll
        for (int i = 0; i < 4; ++i) {
            const int row = ar + 32 * i;
            uint4 av;
            av.x = pack_bf16x2(a0[i].x, a0[i].y);
            av.y = pack_bf16x2(a0[i].z, a0[i].w);
            av.z = pack_bf16x2(a1[i].x, a1[i].y);
            av.w = pack_bf16x2(a1[i].z, a1[i].w);
            *(uint4*)&Atile[row * LDT + ach * 8] = av;

            const float s0 = sc[i];
            unsigned int wv[4] = {(unsigned int)wL[i].x, (unsigned int)wL[i].y,
                                  (unsigned int)wL[i].z, (unsigned int)wL[i].w};
            unsigned int od[4];
#pragma unroll
            for (int j = 0; j < 4; ++j) {
                const unsigned int pair = T2[wv[j] & 0xFFu];
                const float fe = __uint_as_float(pair << 16) * s0;
                const float fo = __uint_as_float(pair & 0xFFFF0000u) * s0;
                od[j] = pack_bf16x2(fe, fo);
            }
            uint4 ov; ov.x = od[0]; ov.y = od[1]; ov.z = od[2]; ov.w = od[3];
            *(uint4*)&Btile[row * LDT + ach * 8] = ov;
        }
        __syncthreads();

#pragma unroll
        for (int k2 = 0; k2 < 2; ++k2) {
            const int ks = k2 * 32 + (lane >> 4) * 8;
            short8 af[4], bfv[4];
#pragma unroll
            for (int i = 0; i < 4; ++i)
                af[i] = *(const short8*)&Atile[(wm + i * 16 + (lane & 15)) * LDT + ks];
#pragma unroll
            for (int j = 0; j < 4; ++j)
                bfv[j] = *(const short8*)&Btile[(wn + j * 16 + (lane & 15)) * LDT + ks];
#pragma unroll
            for (int i = 0; i < 4; ++i)
#pragma unroll
                for (int j = 0; j < 4; ++j)
                    acc[i][j] = __builtin_amdgcn_mfma_f32_16x16x32_bf16(
                        af[i], bfv[j], acc[i][j], 0, 0, 0);
        }
        __syncthreads();
    }

#pragma unroll
    for (int j = 0; j < 4; ++j) {
        const int col = n0 + wn + j * 16 + (lane & 15);
        const float bj = Bias[col];
#pragma unroll
        for (int i = 0; i < 4; ++i) {
            const int rowb = m0 + wm + i * 16 + ((lane >> 4) << 2);
#pragma unroll
            for (int rr = 0; rr < 4; ++rr) {
                Out[(size_t)(rowb + rr) * O_DIM + col] = acc[i][j][rr] + bj;
            }
        }
    }
}

extern "C" void kernel_launch(void* const* d_in, const int* in_sizes, int n_in,
                              void* d_out, int out_size, void* d_ws, size_t ws_size,
                              hipStream_t stream) {
    const float* X    = (const float*)d_in[0];
    const int*   Wp   = (const int*)d_in[1];
    const float* Smax = (const float*)d_in[2];
    const float* Bias = (const float*)d_in[3];
    float*       Out  = (float*)d_out;

    const int M = in_sizes[0] / K_DIM;   // 4096

    const size_t xb_bytes = (size_t)M * K_DIM * sizeof(unsigned short);      // 33.5 MB
    const size_t wb_bytes = (size_t)O_DIM * K_DIM * sizeof(unsigned short);  // 90.2 MB

    if (ws_size >= xb_bytes + wb_bytes) {
        unsigned short* Xb = (unsigned short*)d_ws;
        unsigned short* Wb = (unsigned short*)((char*)d_ws + xb_bytes);

        const int nchunk_x = (M * K_DIM) / 8;                      // 2,097,152
        cvt_x_kernel<<<dim3(2048), dim3(256), 0, stream>>>(X, Xb, nchunk_x);

        const int nchunk_w = O_DIM * (KP / 4);                     // 5,636,096
        dequant_w_kernel<<<dim3(2048), dim3(256), 0, stream>>>(Wp, Smax, Wb, nchunk_w);

        const int nwg = (M / BM) * (O_DIM / BN);                   // 2752
        gemm_bf16_kernel<<<dim3(nwg), dim3(256), 0, stream>>>(Xb, Wb, Bias, Out, M);
    } else {
        dim3 grid(M / BM, O_DIM / BN);
        nf4_linear_kernel<<<grid, dim3(256), 0, stream>>>(X, Wp, Smax, Bias, Out, M);
    }
}

// Round 3
// 658.239 us; speedup vs baseline: 1.6435x; 1.2407x over previous
//
#include <hip/hip_runtime.h>

typedef __attribute__((ext_vector_type(8))) short short8;
typedef __attribute__((ext_vector_type(4))) float float4v;
typedef unsigned int u32;

#define K_DIM 4096
#define O_DIM 11008
#define KP    2048   // packed int32 per output row (1 byte of codes per int32)
#define NBLK  64     // absmax blocks per row
#define BK    64
#define NT2   (K_DIM / BK)   // 64 K-tiles
#define BM2   256
#define BN2   256
// fused-fallback geometry
#define BM    128
#define BN    128
#define LDT   72

// NF4 table via immediate-literal select tree (no device globals).
__device__ __forceinline__ float nf4_val(int c) {
    float v = -1.0f;
    v = (c == 1)  ? -0.6961928009986877f   : v;
    v = (c == 2)  ? -0.5250730514526367f   : v;
    v = (c == 3)  ? -0.39491748809814453f  : v;
    v = (c == 4)  ? -0.28444138169288635f  : v;
    v = (c == 5)  ? -0.18477343022823334f  : v;
    v = (c == 6)  ? -0.09105003625154495f  : v;
    v = (c == 7)  ? 0.0f                   : v;
    v = (c == 8)  ? 0.07958029955625534f   : v;
    v = (c == 9)  ? 0.16093020141124725f   : v;
    v = (c == 10) ? 0.24611230194568634f   : v;
    v = (c == 11) ? 0.33791524171829224f   : v;
    v = (c == 12) ? 0.44070982933044434f   : v;
    v = (c == 13) ? 0.5626170039176941f    : v;
    v = (c == 14) ? 0.8072066307067871f    : v;
    v = (c == 15) ? 1.0f                   : v;
    return v;
}

__device__ __forceinline__ unsigned short bf16_rne(float f) {
    unsigned int u = __float_as_uint(f);
    u = (u + 0x7FFFu + ((u >> 16) & 1u)) >> 16;
    return (unsigned short)u;
}

__device__ __forceinline__ unsigned int pack_bf16x2(float lo_k, float hi_k) {
    return (unsigned int)bf16_rne(lo_k) | ((unsigned int)bf16_rne(hi_k) << 16);
}

// async global->LDS, 16 B per lane; LDS dest is wave-uniform base + lane*16.
__device__ __forceinline__ void gload_lds16(const unsigned short* g, unsigned short* l) {
    __builtin_amdgcn_global_load_lds((const __attribute__((address_space(1))) u32*)g,
                                     (__attribute__((address_space(3))) u32*)l,
                                     16, 0, 0);
}

// ---------------------------------------------------------------------------
// Prep pass 1: X f32 -> bf16 (memory-bound), grid-stride
// ---------------------------------------------------------------------------
__global__ __launch_bounds__(256) void cvt_x_kernel(
    const float* __restrict__ X, unsigned short* __restrict__ Xb, int nchunk)
{
    const int stride = gridDim.x * 256;
    for (int i = blockIdx.x * 256 + threadIdx.x; i < nchunk; i += stride) {
        const float* p = X + (size_t)i * 8;
        float4v a = *(const float4v*)p;
        float4v b = *(const float4v*)(p + 4);
        uint4 o;
        o.x = pack_bf16x2(a.x, a.y);
        o.y = pack_bf16x2(a.z, a.w);
        o.z = pack_bf16x2(b.x, b.y);
        o.w = pack_bf16x2(b.z, b.w);
        *(uint4*)(Xb + (size_t)i * 8) = o;
    }
}

// ---------------------------------------------------------------------------
// Prep pass 2: NF4 W -> bf16 (dequantized ONCE), grid-stride
// ---------------------------------------------------------------------------
__global__ __launch_bounds__(256) void dequant_w_kernel(
    const int* __restrict__ Wp, const float* __restrict__ Smax,
    unsigned short* __restrict__ Wb, int nchunk)
{
    __shared__ unsigned int T2[256];   // byte -> packed bf16 pair (unscaled)
    {
        const int t = threadIdx.x;
        unsigned int hi = (unsigned int)bf16_rne(nf4_val(t >> 4));
        unsigned int lo = (unsigned int)bf16_rne(nf4_val(t & 15));
        T2[t] = hi | (lo << 16);
    }
    __syncthreads();

    const int stride = gridDim.x * 256;
    for (int idx = blockIdx.x * 256 + threadIdx.x; idx < nchunk; idx += stride) {
        const int row = idx >> 9;        // output row
        const int c   = idx & 511;       // 16B chunk within row (8 bf16 out)

        uint4 wv = *(const uint4*)(Wp + (size_t)row * KP + c * 4);
        const float s0 = Smax[row * NBLK + (c >> 3)];
        unsigned int vv[4] = {wv.x, wv.y, wv.z, wv.w};
        unsigned int od[4];
#pragma unroll
        for (int j = 0; j < 4; ++j) {
            const unsigned int pair = T2[vv[j] & 0xFFu];
            const float fe = __uint_as_float(pair << 16) * s0;           // k even (hi nibble)
            const float fo = __uint_as_float(pair & 0xFFFF0000u) * s0;   // k odd  (lo nibble)
            od[j] = pack_bf16x2(fe, fo);
        }
        uint4 ov; ov.x = od[0]; ov.y = od[1]; ov.z = od[2]; ov.w = od[3];
        *(uint4*)(Wb + (size_t)row * K_DIM + c * 8) = ov;
    }
}

// ---------------------------------------------------------------------------
// Main GEMM: 256x256 tile, 8-wave, 8-phase schedule with counted vmcnt (T3+T4),
// XOR slot-swizzled LDS (T2), setprio around MFMA clusters (T5), XCD swizzle (T1).
//
// LDS map (shorts): buf b (0/1) at b*32768.  Within buf:
//   A k-half h: h*8192 + row*32 + slot*8       (256 rows x 32 k, 16 KB)
//   B k-half h: 16384 + h*8192 + row*32 + slot*8
// Content swizzle: LDS(row, slot) holds global slot (slot ^ (row&3)).
//
// Per K-tile u (buf = u&1), 4 phases:
//  P1: read B(h0,nf0-3)+A(h0,mf0-3); stage (u+1,A,k1); bar; 16 MFMA; bar
//  P2: read A(h0,mf4-7);             stage (u+1,B,k1); bar; 16 MFMA; vmcnt; bar
//  P3: read B(h1,nf0-3)+A(h1,mf0-3); stage (u+2,A,k0); bar; 16 MFMA; bar
//  P4: read A(h1,mf4-7);             stage (u+2,B,k0); bar; 16 MFMA; vmcnt; bar
// Steady-state vmcnt(8) = 4 half-tiles in flight; tails use 4 then 0.
// Stage/consume ledger verified: every region is re-written only after its
// last reader phase's end barrier; every read is preceded by a vmcnt that
// retires its staging loads, followed by a barrier (cross-wave visibility).
// ---------------------------------------------------------------------------
#define VMW8 asm volatile("s_waitcnt vmcnt(8)" ::: "memory")
#define VMW4 asm volatile("s_waitcnt vmcnt(4)" ::: "memory")
#define VMW0 asm volatile("s_waitcnt vmcnt(0)" ::: "memory")
#define VMWNONE ((void)0)

__global__ __launch_bounds__(512, 2) void gemm_bf16_256(
    const unsigned short* __restrict__ Xb,   // [M][4096] bf16
    const unsigned short* __restrict__ Wb,   // [11008][4096] bf16
    const float* __restrict__ Bias,
    float* __restrict__ Out, int M)
{
    __shared__ unsigned short L[65536];   // 128 KiB

    const int t    = threadIdx.x;
    const int lane = t & 63;
    const int w    = t >> 6;             // 8 waves

    // XCD swizzle (gridDim.x divisible by 8)
    const int nm  = M / BM2;             // 16
    const int nwg = gridDim.x;           // 688
    const int wg  = (blockIdx.x & 7) * (nwg >> 3) + (blockIdx.x >> 3);
    const int m0  = (wg % nm) * BM2;
    const int n0  = (wg / nm) * BN2;

    const int wm = (w >> 2) * 128;       // wave M window (0/128)
    const int wn = (w & 3) * 64;         // wave N window (0..192)

    // staging: wave w stages rows [32w, 32w+32) of each 256-row half-tile.
    // lane -> (row = lane>>2, slot = lane&3); source slot pre-swizzled.
    const int srow  = lane >> 2;
    const int sslot = (lane & 3) ^ (srow & 3);
    const unsigned short* srcA = Xb + (size_t)(m0 + w * 32 + srow) * K_DIM + sslot * 8;
    const unsigned short* srcB = Wb + (size_t)(n0 + w * 32 + srow) * K_DIM + sslot * 8;
    unsigned short* ldsA = &L[w * 1024];           // + buf*32768 + h*8192 per use
    unsigned short* ldsB = &L[16384 + w * 1024];

    // fragment reads: row = (wm|wn) + f*16 + (lane&15); wanted slot = lane>>4;
    // swizzled slot = (lane>>4) ^ (row&3) = (lane>>4) ^ (lane&3).
    const int rrow  = lane & 15;
    const int rslot = ((lane >> 4) ^ (lane & 3)) * 8;

#define STAGE(src, ldsbase, bufh, koff)                                          \
    do {                                                                         \
        gload_lds16((src) + (koff), (ldsbase) + (bufh));                         \
        gload_lds16((src) + 16 * K_DIM + (koff), (ldsbase) + (bufh) + 512);      \
    } while (0)

#define AFRAG(b, h, mf) (*(const short8*)&L[(b) * 32768 + (h) * 8192 +            \
                          (wm + (mf) * 16 + rrow) * 32 + rslot])
#define BFRAG(b, h, nf) (*(const short8*)&L[(b) * 32768 + 16384 + (h) * 8192 +    \
                          (wn + (nf) * 16 + rrow) * 32 + rslot])

    float4v acc[8][4] = {};
    short8 af[4], bf[4];

#define MFMA_Q(mbase)                                                             \
    __builtin_amdgcn_s_setprio(1);                                                \
    _Pragma("unroll") for (int mf = 0; mf < 4; ++mf)                              \
        _Pragma("unroll") for (int nf = 0; nf < 4; ++nf)                          \
            acc[(mbase) + mf][nf] = __builtin_amdgcn_mfma_f32_16x16x32_bf16(      \
                af[mf], bf[nf], acc[(mbase) + mf][nf], 0, 0, 0);                  \
    __builtin_amdgcn_s_setprio(0)

#define KTILE(u_, S12_, S34_, VM2_, VM4_)                                         \
    {                                                                             \
        const int b_  = (u_) & 1;                                                 \
        const int kt_ = (u_) * BK;                                                \
        /* P1: h0, mh0 */                                                         \
        _Pragma("unroll") for (int nf = 0; nf < 4; ++nf) bf[nf] = BFRAG(b_, 0, nf); \
        _Pragma("unroll") for (int mf = 0; mf < 4; ++mf) af[mf] = AFRAG(b_, 0, mf); \
        if (S12_) STAGE(srcA, ldsA, (b_ ^ 1) * 32768 + 8192, kt_ + BK + 32);      \
        __builtin_amdgcn_s_barrier();                                             \
        MFMA_Q(0);                                                                \
        __builtin_amdgcn_s_barrier();                                             \
        /* P2: h0, mh1 */                                                         \
        _Pragma("unroll") for (int mf = 0; mf < 4; ++mf) af[mf] = AFRAG(b_, 0, mf + 4); \
        if (S12_) STAGE(srcB, ldsB, (b_ ^ 1) * 32768 + 8192, kt_ + BK + 32);      \
        __builtin_amdgcn_s_barrier();                                             \
        MFMA_Q(4);                                                                \
        VM2_;                                                                     \
        __builtin_amdgcn_s_barrier();                                             \
        /* P3: h1, mh0 */                                                         \
        _Pragma("unroll") for (int nf = 0; nf < 4; ++nf) bf[nf] = BFRAG(b_, 1, nf); \
        _Pragma("unroll") for (int mf = 0; mf < 4; ++mf) af[mf] = AFRAG(b_, 1, mf); \
        if (S34_) STAGE(srcA, ldsA, b_ * 32768, kt_ + 2 * BK);                    \
        __builtin_amdgcn_s_barrier();                                             \
        MFMA_Q(0);                                                                \
        __builtin_amdgcn_s_barrier();                                             \
        /* P4: h1, mh1 */                                                         \
        _Pragma("unroll") for (int mf = 0; mf < 4; ++mf) af[mf] = AFRAG(b_, 1, mf + 4); \
        if (S34_) STAGE(srcB, ldsB, b_ * 32768, kt_ + 2 * BK);                    \
        __builtin_amdgcn_s_barrier();                                             \
        MFMA_Q(4);                                                                \
        VM4_;                                                                     \
        __builtin_amdgcn_s_barrier();                                             \
    }

    // ---- prologue: stage (0,k0),(0,k1),(1,k0); retire (0,k0); barrier ----
    STAGE(srcA, ldsA, 0,            0);    // (0,A,k0)
    STAGE(srcB, ldsB, 0,            0);    // (0,B,k0)
    STAGE(srcA, ldsA, 8192,         32);   // (0,A,k1)
    STAGE(srcB, ldsB, 8192,         32);   // (0,B,k1)
    STAGE(srcA, ldsA, 32768,        64);   // (1,A,k0)
    STAGE(srcB, ldsB, 32768,        64);   // (1,B,k0)
    VMW8;
    __builtin_amdgcn_s_barrier();

    // ---- steady loop + peeled tails ----
    for (int u = 0; u < NT2 - 2; ++u)
        KTILE(u, true, true, VMW8, VMW8);
    KTILE(NT2 - 2, true, false, VMW8, VMW4);
    KTILE(NT2 - 1, false, false, VMW0, VMWNONE);

    // ---- epilogue: D col = lane&15, row = (lane>>4)*4 + reg ----
#pragma unroll
    for (int nf = 0; nf < 4; ++nf) {
        const int col = n0 + wn + nf * 16 + (lane & 15);
        const float bj = Bias[col];
#pragma unroll
        for (int mf = 0; mf < 8; ++mf) {
            const int rowb = m0 + wm + mf * 16 + ((lane >> 4) << 2);
#pragma unroll
            for (int rr = 0; rr < 4; ++rr) {
                Out[(size_t)(rowb + rr) * O_DIM + col] = acc[mf][nf][rr] + bj;
            }
        }
    }
#undef STAGE
#undef AFRAG
#undef BFRAG
#undef MFMA_Q
#undef KTILE
}

// ---------------------------------------------------------------------------
// Fused fallback (verified) — used if workspace too small or M%256 != 0
// ---------------------------------------------------------------------------
__global__ __launch_bounds__(256) void nf4_linear_kernel(
    const float* __restrict__ X,
    const int* __restrict__ Wp,
    const float* __restrict__ Smax,
    const float* __restrict__ Bias,
    float* __restrict__ Out,
    int M)
{
    __shared__ unsigned short Atile[BM * LDT];
    __shared__ unsigned short Btile[BN * LDT];
    __shared__ unsigned int   T2[256];

    const int t = threadIdx.x;
    const int m0 = blockIdx.x * BM;
    const int n0 = blockIdx.y * BN;

    {
        unsigned int hi = (unsigned int)bf16_rne(nf4_val(t >> 4));
        unsigned int lo = (unsigned int)bf16_rne(nf4_val(t & 15));
        T2[t] = hi | (lo << 16);
    }
    __syncthreads();

    const int lane = t & 63;
    const int wave = t >> 6;
    const int wm = (wave >> 1) * 64;
    const int wn = (wave & 1) * 64;
    const int ar = t >> 3;
    const int ach = t & 7;

    float4v acc[4][4] = {};

    for (int s = 0; s < K_DIM / BK; ++s) {
        const int kt = s * BK;
        float4v a0[4], a1[4]; uint4 wL[4]; float sc[4];
#pragma unroll
        for (int i = 0; i < 4; ++i) {
            const int row = ar + 32 * i;
            const float* ap = X + (size_t)(m0 + row) * K_DIM + kt + ach * 8;
            a0[i] = *(const float4v*)ap;
            a1[i] = *(const float4v*)(ap + 4);
            wL[i] = *(const uint4*)(Wp + (size_t)(n0 + row) * KP + (kt >> 1) + ach * 4);
            sc[i] = Smax[(n0 + row) * NBLK + s];
        }
#pragma unroll
        for (int i = 0; i < 4; ++i) {
            const int row = ar + 32 * i;
            uint4 av;
            av.x = pack_bf16x2(a0[i].x, a0[i].y);
            av.y = pack_bf16x2(a0[i].z, a0[i].w);
            av.z = pack_bf16x2(a1[i].x, a1[i].y);
            av.w = pack_bf16x2(a1[i].z, a1[i].w);
            *(uint4*)&Atile[row * LDT + ach * 8] = av;

            const float s0 = sc[i];
            unsigned int wv[4] = {(unsigned int)wL[i].x, (unsigned int)wL[i].y,
                                  (unsigned int)wL[i].z, (unsigned int)wL[i].w};
            unsigned int od[4];
#pragma unroll
            for (int j = 0; j < 4; ++j) {
                const unsigned int pair = T2[wv[j] & 0xFFu];
                const float fe = __uint_as_float(pair << 16) * s0;
                const float fo = __uint_as_float(pair & 0xFFFF0000u) * s0;
                od[j] = pack_bf16x2(fe, fo);
            }
            uint4 ov; ov.x = od[0]; ov.y = od[1]; ov.z = od[2]; ov.w = od[3];
            *(uint4*)&Btile[row * LDT + ach * 8] = ov;
        }
        __syncthreads();

#pragma unroll
        for (int k2 = 0; k2 < 2; ++k2) {
            const int ks = k2 * 32 + (lane >> 4) * 8;
            short8 afv[4], bfv[4];
#pragma unroll
            for (int i = 0; i < 4; ++i)
                afv[i] = *(const short8*)&Atile[(wm + i * 16 + (lane & 15)) * LDT + ks];
#pragma unroll
            for (int j = 0; j < 4; ++j)
                bfv[j] = *(const short8*)&Btile[(wn + j * 16 + (lane & 15)) * LDT + ks];
#pragma unroll
            for (int i = 0; i < 4; ++i)
#pragma unroll
                for (int j = 0; j < 4; ++j)
                    acc[i][j] = __builtin_amdgcn_mfma_f32_16x16x32_bf16(
                        afv[i], bfv[j], acc[i][j], 0, 0, 0);
        }
        __syncthreads();
    }

#pragma unroll
    for (int j = 0; j < 4; ++j) {
        const int col = n0 + wn + j * 16 + (lane & 15);
        const float bj = Bias[col];
#pragma unroll
        for (int i = 0; i < 4; ++i) {
            const int rowb = m0 + wm + i * 16 + ((lane >> 4) << 2);
#pragma unroll
            for (int rr = 0; rr < 4; ++rr) {
                Out[(size_t)(rowb + rr) * O_DIM + col] = acc[i][j][rr] + bj;
            }
        }
    }
}

extern "C" void kernel_launch(void* const* d_in, const int* in_sizes, int n_in,
                              void* d_out, int out_size, void* d_ws, size_t ws_size,
                              hipStream_t stream) {
    const float* X    = (const float*)d_in[0];
    const int*   Wp   = (const int*)d_in[1];
    const float* Smax = (const float*)d_in[2];
    const float* Bias = (const float*)d_in[3];
    float*       Out  = (float*)d_out;

    const int M = in_sizes[0] / K_DIM;   // 4096

    const size_t xb_bytes = (size_t)M * K_DIM * sizeof(unsigned short);      // 33.5 MB
    const size_t wb_bytes = (size_t)O_DIM * K_DIM * sizeof(unsigned short);  // 90.2 MB

    if (ws_size >= xb_bytes + wb_bytes && (M % BM2) == 0) {
        unsigned short* Xb = (unsigned short*)d_ws;
        unsigned short* Wb = (unsigned short*)((char*)d_ws + xb_bytes);

        const int nchunk_x = (M * K_DIM) / 8;
        cvt_x_kernel<<<dim3(2048), dim3(256), 0, stream>>>(X, Xb, nchunk_x);

        const int nchunk_w = O_DIM * (KP / 4);
        dequant_w_kernel<<<dim3(2048), dim3(256), 0, stream>>>(Wp, Smax, Wb, nchunk_w);

        const int nwg = (M / BM2) * (O_DIM / BN2);    // 16*43 = 688, divisible by 8
        gemm_bf16_256<<<dim3(nwg), dim3(512), 0, stream>>>(Xb, Wb, Bias, Out, M);
    } else {
        dim3 grid(M / BM, O_DIM / BN);
        nf4_linear_kernel<<<grid, dim3(256), 0, stream>>>(X, Wp, Smax, Bias, Out, M);
    }
}

// Round 4
// 642.325 us; speedup vs baseline: 1.6842x; 1.0248x over previous
//
#include <hip/hip_runtime.h>

typedef __attribute__((ext_vector_type(8))) short short8;
typedef __attribute__((ext_vector_type(4))) float float4v;
typedef unsigned int u32;

#define K_DIM 4096
#define O_DIM 11008
#define KP    2048   // packed int32 per output row (1 byte of codes per int32)
#define NBLK  64     // absmax blocks per row
#define BK    64
#define NT2   (K_DIM / BK)   // 64 K-tiles
#define BM2   256
#define BN2   256
// fused-fallback geometry
#define BM    128
#define BN    128
#define LDT   72

// NF4 table via immediate-literal select tree (no device globals).
__device__ __forceinline__ float nf4_val(int c) {
    float v = -1.0f;
    v = (c == 1)  ? -0.6961928009986877f   : v;
    v = (c == 2)  ? -0.5250730514526367f   : v;
    v = (c == 3)  ? -0.39491748809814453f  : v;
    v = (c == 4)  ? -0.28444138169288635f  : v;
    v = (c == 5)  ? -0.18477343022823334f  : v;
    v = (c == 6)  ? -0.09105003625154495f  : v;
    v = (c == 7)  ? 0.0f                   : v;
    v = (c == 8)  ? 0.07958029955625534f   : v;
    v = (c == 9)  ? 0.16093020141124725f   : v;
    v = (c == 10) ? 0.24611230194568634f   : v;
    v = (c == 11) ? 0.33791524171829224f   : v;
    v = (c == 12) ? 0.44070982933044434f   : v;
    v = (c == 13) ? 0.5626170039176941f    : v;
    v = (c == 14) ? 0.8072066307067871f    : v;
    v = (c == 15) ? 1.0f                   : v;
    return v;
}

__device__ __forceinline__ unsigned short bf16_rne(float f) {
    unsigned int u = __float_as_uint(f);
    u = (u + 0x7FFFu + ((u >> 16) & 1u)) >> 16;
    return (unsigned short)u;
}

__device__ __forceinline__ unsigned int pack_bf16x2(float lo_k, float hi_k) {
    return (unsigned int)bf16_rne(lo_k) | ((unsigned int)bf16_rne(hi_k) << 16);
}

// async global->LDS, 16 B per lane; LDS dest is wave-uniform base + lane*16.
__device__ __forceinline__ void gload_lds16(const unsigned short* g, unsigned short* l) {
    __builtin_amdgcn_global_load_lds((const __attribute__((address_space(1))) u32*)g,
                                     (__attribute__((address_space(3))) u32*)l,
                                     16, 0, 0);
}

// ---------------------------------------------------------------------------
// Fused prep: (a) NF4 W -> bf16 (dequantized ONCE), (b) X f32 -> bf16.
// One launch instead of two; both loops grid-strided.
// ---------------------------------------------------------------------------
__global__ __launch_bounds__(256) void prep_kernel(
    const float* __restrict__ X, unsigned short* __restrict__ Xb, int nchunk_x,
    const int* __restrict__ Wp, const float* __restrict__ Smax,
    unsigned short* __restrict__ Wb, int nchunk_w)
{
    __shared__ unsigned int T2[256];   // byte -> packed bf16 pair (unscaled)
    {
        const int t = threadIdx.x;
        unsigned int hi = (unsigned int)bf16_rne(nf4_val(t >> 4));
        unsigned int lo = (unsigned int)bf16_rne(nf4_val(t & 15));
        T2[t] = hi | (lo << 16);
    }
    __syncthreads();

    const int stride = gridDim.x * 256;
    const int g0 = blockIdx.x * 256 + threadIdx.x;

    for (int idx = g0; idx < nchunk_w; idx += stride) {
        const int row = idx >> 9;        // output row
        const int c   = idx & 511;       // 16B chunk within row (8 bf16 out)

        uint4 wv = *(const uint4*)(Wp + (size_t)row * KP + c * 4);
        const float s0 = Smax[row * NBLK + (c >> 3)];
        unsigned int vv[4] = {wv.x, wv.y, wv.z, wv.w};
        unsigned int od[4];
#pragma unroll
        for (int j = 0; j < 4; ++j) {
            const unsigned int pair = T2[vv[j] & 0xFFu];
            const float fe = __uint_as_float(pair << 16) * s0;           // k even (hi nibble)
            const float fo = __uint_as_float(pair & 0xFFFF0000u) * s0;   // k odd  (lo nibble)
            od[j] = pack_bf16x2(fe, fo);
        }
        uint4 ov; ov.x = od[0]; ov.y = od[1]; ov.z = od[2]; ov.w = od[3];
        *(uint4*)(Wb + (size_t)row * K_DIM + c * 8) = ov;
    }

    for (int i = g0; i < nchunk_x; i += stride) {
        const float* p = X + (size_t)i * 8;
        float4v a = *(const float4v*)p;
        float4v b = *(const float4v*)(p + 4);
        uint4 o;
        o.x = pack_bf16x2(a.x, a.y);
        o.y = pack_bf16x2(a.z, a.w);
        o.z = pack_bf16x2(b.x, b.y);
        o.w = pack_bf16x2(b.z, b.w);
        *(uint4*)(Xb + (size_t)i * 8) = o;
    }
}

// ---------------------------------------------------------------------------
// Main GEMM: 256x256 tile, 8-wave, 8-phase schedule with counted vmcnt (T3+T4),
// XOR slot-swizzled LDS (T2), setprio around MFMA clusters (T5), XCD swizzle (T1).
//
// LDS map (shorts): buf b (0/1) at b*32768.  Within buf:
//   A k-half h: h*8192 + row*32 + slot*8       (256 rows x 32 k, 16 KB)
//   B k-half h: 16384 + h*8192 + row*32 + slot*8
//
// SWIZZLE (round-4 fix): rows are 64 B = 4 slots; bankgroup = (row*4+slot')&7
// only sees row bit0 (x4) and slot'.  XOR by (row&3) wasted a bit ->
// 4-way conflicts (3.4e7 measured).  New involution: slot' = slot ^ ((row>>1)&3).
// Over a 16-lane quarter (rows 0..15, fixed wanted slot), (row&1,(row>>1)&3)
// covers all 8 bankgroups exactly twice -> 2-way = free (m136).
//
// Per K-tile u (buf = u&1), 4 phases:
//  P1: read B(h0,nf0-3)+A(h0,mf0-3); stage (u+1,A,k1); bar; 16 MFMA; bar
//  P2: read A(h0,mf4-7);             stage (u+1,B,k1); bar; 16 MFMA; vmcnt; bar
//  P3: read B(h1,nf0-3)+A(h1,mf0-3); stage (u+2,A,k0); bar; 16 MFMA; bar
//  P4: read A(h1,mf4-7);             stage (u+2,B,k0); bar; 16 MFMA; vmcnt; bar
// Steady-state vmcnt(8) = 4 half-tiles in flight; tails use 4 then 0.
// ---------------------------------------------------------------------------
#define VMW8 asm volatile("s_waitcnt vmcnt(8)" ::: "memory")
#define VMW4 asm volatile("s_waitcnt vmcnt(4)" ::: "memory")
#define VMW0 asm volatile("s_waitcnt vmcnt(0)" ::: "memory")
#define VMWNONE ((void)0)

__global__ __launch_bounds__(512, 2) void gemm_bf16_256(
    const unsigned short* __restrict__ Xb,   // [M][4096] bf16
    const unsigned short* __restrict__ Wb,   // [11008][4096] bf16
    const float* __restrict__ Bias,
    float* __restrict__ Out, int M)
{
    __shared__ unsigned short L[65536];   // 128 KiB

    const int t    = threadIdx.x;
    const int lane = t & 63;
    const int w    = t >> 6;             // 8 waves

    // XCD swizzle (gridDim.x divisible by 8)
    const int nm  = M / BM2;             // 16
    const int nwg = gridDim.x;           // 688
    const int wg  = (blockIdx.x & 7) * (nwg >> 3) + (blockIdx.x >> 3);
    const int m0  = (wg % nm) * BM2;
    const int n0  = (wg / nm) * BN2;

    const int wm = (w >> 2) * 128;       // wave M window (0/128)
    const int wn = (w & 3) * 64;         // wave N window (0..192)

    // staging: wave w stages rows [32w, 32w+32) of each 256-row half-tile.
    // lane -> (row = lane>>2, slot = lane&3); source slot pre-swizzled:
    // fetch global slot (lane&3) ^ ((row>>1)&3), row>>1 = lane>>3 (stripe
    // bases are multiples of 16 so they don't affect (row>>1)&3).
    const int srow  = lane >> 2;
    const int sslot = (lane & 3) ^ ((lane >> 3) & 3);
    const unsigned short* srcA = Xb + (size_t)(m0 + w * 32 + srow) * K_DIM + sslot * 8;
    const unsigned short* srcB = Wb + (size_t)(n0 + w * 32 + srow) * K_DIM + sslot * 8;
    unsigned short* ldsA = &L[w * 1024];           // + buf*32768 + h*8192 per use
    unsigned short* ldsB = &L[16384 + w * 1024];

    // fragment reads: row = (wm|wn) + f*16 + (lane&15); wanted slot = lane>>4;
    // stored slot = wanted ^ ((row>>1)&3) = (lane>>4) ^ ((lane>>1)&3).
    const int rrow  = lane & 15;
    const int rslot = ((lane >> 4) ^ ((lane >> 1) & 3)) * 8;

#define STAGE(src, ldsbase, bufh, koff)                                          \
    do {                                                                         \
        gload_lds16((src) + (koff), (ldsbase) + (bufh));                         \
        gload_lds16((src) + 16 * K_DIM + (koff), (ldsbase) + (bufh) + 512);      \
    } while (0)

#define AFRAG(b, h, mf) (*(const short8*)&L[(b) * 32768 + (h) * 8192 +            \
                          (wm + (mf) * 16 + rrow) * 32 + rslot])
#define BFRAG(b, h, nf) (*(const short8*)&L[(b) * 32768 + 16384 + (h) * 8192 +    \
                          (wn + (nf) * 16 + rrow) * 32 + rslot])

    float4v acc[8][4] = {};
    short8 af[4], bf[4];

#define MFMA_Q(mbase)                                                             \
    __builtin_amdgcn_s_setprio(1);                                                \
    _Pragma("unroll") for (int mf = 0; mf < 4; ++mf)                              \
        _Pragma("unroll") for (int nf = 0; nf < 4; ++nf)                          \
            acc[(mbase) + mf][nf] = __builtin_amdgcn_mfma_f32_16x16x32_bf16(      \
                af[mf], bf[nf], acc[(mbase) + mf][nf], 0, 0, 0);                  \
    __builtin_amdgcn_s_setprio(0)

#define KTILE(u_, S12_, S34_, VM2_, VM4_)                                         \
    {                                                                             \
        const int b_  = (u_) & 1;                                                 \
        const int kt_ = (u_) * BK;                                                \
        /* P1: h0, mh0 */                                                         \
        _Pragma("unroll") for (int nf = 0; nf < 4; ++nf) bf[nf] = BFRAG(b_, 0, nf); \
        _Pragma("unroll") for (int mf = 0; mf < 4; ++mf) af[mf] = AFRAG(b_, 0, mf); \
        if (S12_) STAGE(srcA, ldsA, (b_ ^ 1) * 32768 + 8192, kt_ + BK + 32);      \
        __builtin_amdgcn_s_barrier();                                             \
        MFMA_Q(0);                                                                \
        __builtin_amdgcn_s_barrier();                                             \
        /* P2: h0, mh1 */                                                         \
        _Pragma("unroll") for (int mf = 0; mf < 4; ++mf) af[mf] = AFRAG(b_, 0, mf + 4); \
        if (S12_) STAGE(srcB, ldsB, (b_ ^ 1) * 32768 + 8192, kt_ + BK + 32);      \
        __builtin_amdgcn_s_barrier();                                             \
        MFMA_Q(4);                                                                \
        VM2_;                                                                     \
        __builtin_amdgcn_s_barrier();                                             \
        /* P3: h1, mh0 */                                                         \
        _Pragma("unroll") for (int nf = 0; nf < 4; ++nf) bf[nf] = BFRAG(b_, 1, nf); \
        _Pragma("unroll") for (int mf = 0; mf < 4; ++mf) af[mf] = AFRAG(b_, 1, mf); \
        if (S34_) STAGE(srcA, ldsA, b_ * 32768, kt_ + 2 * BK);                    \
        __builtin_amdgcn_s_barrier();                                             \
        MFMA_Q(0);                                                                \
        __builtin_amdgcn_s_barrier();                                             \
        /* P4: h1, mh1 */                                                         \
        _Pragma("unroll") for (int mf = 0; mf < 4; ++mf) af[mf] = AFRAG(b_, 1, mf + 4); \
        if (S34_) STAGE(srcB, ldsB, b_ * 32768, kt_ + 2 * BK);                    \
        __builtin_amdgcn_s_barrier();                                             \
        MFMA_Q(4);                                                                \
        VM4_;                                                                     \
        __builtin_amdgcn_s_barrier();                                             \
    }

    // ---- prologue: stage (0,k0),(0,k1),(1,k0); retire (0,*); barrier ----
    STAGE(srcA, ldsA, 0,            0);    // (0,A,k0)
    STAGE(srcB, ldsB, 0,            0);    // (0,B,k0)
    STAGE(srcA, ldsA, 8192,         32);   // (0,A,k1)
    STAGE(srcB, ldsB, 8192,         32);   // (0,B,k1)
    STAGE(srcA, ldsA, 32768,        64);   // (1,A,k0)
    STAGE(srcB, ldsB, 32768,        64);   // (1,B,k0)
    VMW8;
    __builtin_amdgcn_s_barrier();

    // ---- steady loop + peeled tails ----
    for (int u = 0; u < NT2 - 2; ++u)
        KTILE(u, true, true, VMW8, VMW8);
    KTILE(NT2 - 2, true, false, VMW8, VMW4);
    KTILE(NT2 - 1, false, false, VMW0, VMWNONE);

    // ---- epilogue: D col = lane&15, row = (lane>>4)*4 + reg ----
#pragma unroll
    for (int nf = 0; nf < 4; ++nf) {
        const int col = n0 + wn + nf * 16 + (lane & 15);
        const float bj = Bias[col];
#pragma unroll
        for (int mf = 0; mf < 8; ++mf) {
            const int rowb = m0 + wm + mf * 16 + ((lane >> 4) << 2);
#pragma unroll
            for (int rr = 0; rr < 4; ++rr) {
                Out[(size_t)(rowb + rr) * O_DIM + col] = acc[mf][nf][rr] + bj;
            }
        }
    }
#undef STAGE
#undef AFRAG
#undef BFRAG
#undef MFMA_Q
#undef KTILE
}

// ---------------------------------------------------------------------------
// Fused fallback (verified) — used if workspace too small or M%256 != 0
// ---------------------------------------------------------------------------
__global__ __launch_bounds__(256) void nf4_linear_kernel(
    const float* __restrict__ X,
    const int* __restrict__ Wp,
    const float* __restrict__ Smax,
    const float* __restrict__ Bias,
    float* __restrict__ Out,
    int M)
{
    __shared__ unsigned short Atile[BM * LDT];
    __shared__ unsigned short Btile[BN * LDT];
    __shared__ unsigned int   T2[256];

    const int t = threadIdx.x;
    const int m0 = blockIdx.x * BM;
    const int n0 = blockIdx.y * BN;

    {
        unsigned int hi = (unsigned int)bf16_rne(nf4_val(t >> 4));
        unsigned int lo = (unsigned int)bf16_rne(nf4_val(t & 15));
        T2[t] = hi | (lo << 16);
    }
    __syncthreads();

    const int lane = t & 63;
    const int wave = t >> 6;
    const int wm = (wave >> 1) * 64;
    const int wn = (wave & 1) * 64;
    const int ar = t >> 3;
    const int ach = t & 7;

    float4v acc[4][4] = {};

    for (int s = 0; s < K_DIM / BK; ++s) {
        const int kt = s * BK;
        float4v a0[4], a1[4]; uint4 wL[4]; float sc[4];
#pragma unroll
        for (int i = 0; i < 4; ++i) {
            const int row = ar + 32 * i;
            const float* ap = X + (size_t)(m0 + row) * K_DIM + kt + ach * 8;
            a0[i] = *(const float4v*)ap;
            a1[i] = *(const float4v*)(ap + 4);
            wL[i] = *(const uint4*)(Wp + (size_t)(n0 + row) * KP + (kt >> 1) + ach * 4);
            sc[i] = Smax[(n0 + row) * NBLK + s];
        }
#pragma unroll
        for (int i = 0; i < 4; ++i) {
            const int row = ar + 32 * i;
            uint4 av;
            av.x = pack_bf16x2(a0[i].x, a0[i].y);
            av.y = pack_bf16x2(a0[i].z, a0[i].w);
            av.z = pack_bf16x2(a1[i].x, a1[i].y);
            av.w = pack_bf16x2(a1[i].z, a1[i].w);
            *(uint4*)&Atile[row * LDT + ach * 8] = av;

            const float s0 = sc[i];
            unsigned int wv[4] = {(unsigned int)wL[i].x, (unsigned int)wL[i].y,
                                  (unsigned int)wL[i].z, (unsigned int)wL[i].w};
            unsigned int od[4];
#pragma unroll
            for (int j = 0; j < 4; ++j) {
                const unsigned int pair = T2[wv[j] & 0xFFu];
                const float fe = __uint_as_float(pair << 16) * s0;
                const float fo = __uint_as_float(pair & 0xFFFF0000u) * s0;
                od[j] = pack_bf16x2(fe, fo);
            }
            uint4 ov; ov.x = od[0]; ov.y = od[1]; ov.z = od[2]; ov.w = od[3];
            *(uint4*)&Btile[row * LDT + ach * 8] = ov;
        }
        __syncthreads();

#pragma unroll
        for (int k2 = 0; k2 < 2; ++k2) {
            const int ks = k2 * 32 + (lane >> 4) * 8;
            short8 afv[4], bfv[4];
#pragma unroll
            for (int i = 0; i < 4; ++i)
                afv[i] = *(const short8*)&Atile[(wm + i * 16 + (lane & 15)) * LDT + ks];
#pragma unroll
            for (int j = 0; j < 4; ++j)
                bfv[j] = *(const short8*)&Btile[(wn + j * 16 + (lane & 15)) * LDT + ks];
#pragma unroll
            for (int i = 0; i < 4; ++i)
#pragma unroll
                for (int j = 0; j < 4; ++j)
                    acc[i][j] = __builtin_amdgcn_mfma_f32_16x16x32_bf16(
                        afv[i], bfv[j], acc[i][j], 0, 0, 0);
        }
        __syncthreads();
    }

#pragma unroll
    for (int j = 0; j < 4; ++j) {
        const int col = n0 + wn + j * 16 + (lane & 15);
        const float bj = Bias[col];
#pragma unroll
        for (int i = 0; i < 4; ++i) {
            const int rowb = m0 + wm + i * 16 + ((lane >> 4) << 2);
#pragma unroll
            for (int rr = 0; rr < 4; ++rr) {
                Out[(size_t)(rowb + rr) * O_DIM + col] = acc[i][j][rr] + bj;
            }
        }
    }
}

extern "C" void kernel_launch(void* const* d_in, const int* in_sizes, int n_in,
                              void* d_out, int out_size, void* d_ws, size_t ws_size,
                              hipStream_t stream) {
    const float* X    = (const float*)d_in[0];
    const int*   Wp   = (const int*)d_in[1];
    const float* Smax = (const float*)d_in[2];
    const float* Bias = (const float*)d_in[3];
    float*       Out  = (float*)d_out;

    const int M = in_sizes[0] / K_DIM;   // 4096

    const size_t xb_bytes = (size_t)M * K_DIM * sizeof(unsigned short);      // 33.5 MB
    const size_t wb_bytes = (size_t)O_DIM * K_DIM * sizeof(unsigned short);  // 90.2 MB

    if (ws_size >= xb_bytes + wb_bytes && (M % BM2) == 0) {
        unsigned short* Xb = (unsigned short*)d_ws;
        unsigned short* Wb = (unsigned short*)((char*)d_ws + xb_bytes);

        const int nchunk_x = (M * K_DIM) / 8;        // 2,097,152
        const int nchunk_w = O_DIM * (KP / 4);       // 5,636,096
        prep_kernel<<<dim3(2048), dim3(256), 0, stream>>>(
            X, Xb, nchunk_x, Wp, Smax, Wb, nchunk_w);

        const int nwg = (M / BM2) * (O_DIM / BN2);    // 16*43 = 688, divisible by 8
        gemm_bf16_256<<<dim3(nwg), dim3(512), 0, stream>>>(Xb, Wb, Bias, Out, M);
    } else {
        dim3 grid(M / BM, O_DIM / BN);
        nf4_linear_kernel<<<grid, dim3(256), 0, stream>>>(X, Wp, Smax, Bias, Out, M);
    }
}